// Round 13
// baseline (136.972 us; speedup 1.0000x reference)
//
#include <hip/hip_runtime.h>
#include <math.h>

#define G      32
#define NCELLS (G * G * G)        // 32768
#define LOF    (-6.0f)
#define HH     0.375f             // 12/32
#define INVH   (1.0f / 0.375f)
#define DELTA  1e-3f              // accept/prune slack >> fp d2 rounding (~1e-5)

__device__ __forceinline__ int cell_coord(float x) {
    int c = (int)floorf((x - LOF) * INVH);
    c = c < 0 ? 0 : c;
    return c > G - 1 ? G - 1 : c;
}
__device__ __forceinline__ int imax2(int a, int b) { return a > b ? a : b; }
__device__ __forceinline__ int imin2(int a, int b) { return a < b ? a : b; }
__device__ __forceinline__ int iabs(int a) { return a < 0 ? -a : a; }
__device__ __forceinline__ float rdfl(float v) {
    return __int_as_float(__builtin_amdgcn_readfirstlane(__float_as_int(v)));
}

// lexicographic (d, idx) 3-slot insert == jax top_k tie semantics (order-free)
#define LEXINSERT(dv, jv) do {                                        \
    float d_ = (dv); int j_ = (jv);                                   \
    bool l0 = (d_ < e0) || ((d_ == e0) && (j_ < i0));                 \
    bool l1 = (d_ < e1) || ((d_ == e1) && (j_ < i1));                 \
    bool l2 = (d_ < e2) || ((d_ == e2) && (j_ < i2));                 \
    int   ni0 = l0 ? j_ : i0;                                         \
    int   ni1 = l0 ? i0 : (l1 ? j_ : i1);                             \
    int   ni2 = l1 ? i1 : (l2 ? j_ : i2);                             \
    float ne0 = l0 ? d_ : e0;                                         \
    float ne1 = l0 ? e0 : (l1 ? d_ : e1);                             \
    float ne2 = l1 ? e1 : (l2 ? d_ : e2);                             \
    e0 = ne0; e1 = ne1; e2 = ne2; i0 = ni0; i1 = ni1; i2 = ni2;       \
} while (0)

// lanes split refs [lo,hi) of a contiguous run; coalesced float4 loads.
// d2 chain bit-identical to the passing kernels (contract off in caller).
#define SCAN_RUN(lo_, hi_) do {                                       \
    for (int u = (lo_) + lane; u < (hi_); u += 64) {                  \
        float4 rr = srt[u];                                           \
        float xx = rr.x * rr.x;                                       \
        float yy = rr.y * rr.y;                                       \
        float zz = rr.z * rr.z;                                       \
        float r2 = (xx + yy) + zz;                                    \
        float td = qx * rr.x;                                         \
        td = fmaf(qy, rr.y, td);                                      \
        td = fmaf(qz, rr.z, td);                                      \
        float aa = q2 + r2;                                           \
        float dd = fmaf(-2.0f, td, aa);                               \
        int jj = __float_as_int(rr.w);                                \
        LEXINSERT(dd, jj);                                            \
    }                                                                 \
} while (0)

// 64-lane butterfly lex-merge of per-lane top-3 sets
#define MERGE64() do {                                                \
    _Pragma("unroll")                                                 \
    for (int mk_ = 1; mk_ < 64; mk_ <<= 1) {                          \
        float f0 = __shfl_xor(e0, mk_, 64);                           \
        float f1 = __shfl_xor(e1, mk_, 64);                           \
        float f2 = __shfl_xor(e2, mk_, 64);                           \
        int   g0 = __shfl_xor(i0, mk_, 64);                           \
        int   g1 = __shfl_xor(i1, mk_, 64);                           \
        int   g2 = __shfl_xor(i2, mk_, 64);                           \
        LEXINSERT(f0, g0);                                            \
        LEXINSERT(f1, g1);                                            \
        LEXINSERT(f2, g2);                                            \
    }                                                                 \
} while (0)

// 32-lane butterfly: masks 1..16 never cross the 32-lane group boundary, so
// the SAME instructions merge both queries of the wave simultaneously.
#define MERGE32() do {                                                \
    _Pragma("unroll")                                                 \
    for (int mk_ = 1; mk_ < 32; mk_ <<= 1) {                          \
        float f0 = __shfl_xor(e0, mk_, 64);                           \
        float f1 = __shfl_xor(e1, mk_, 64);                           \
        float f2 = __shfl_xor(e2, mk_, 64);                           \
        int   g0 = __shfl_xor(i0, mk_, 64);                           \
        int   g1 = __shfl_xor(i1, mk_, 64);                           \
        int   g2 = __shfl_xor(i2, mk_, 64);                           \
        LEXINSERT(f0, g0);                                            \
        LEXINSERT(f1, g1);                                            \
        LEXINSERT(f2, g2);                                            \
    }                                                                 \
} while (0)

// clamp + weights + gather + store, reference op order
#define EPILOGUE() do {                                               \
    e0 = fmaxf(e0, 0.0f);                                             \
    e1 = fmaxf(e1, 0.0f);                                             \
    e2 = fmaxf(e2, 0.0f);                                             \
    float s0 = sqrtf(e0);                                             \
    float s1 = sqrtf(e1);                                             \
    float s2 = sqrtf(e2);                                             \
    float w0 = 1.0f / (s0 + 1e-8f);                                   \
    float w1 = 1.0f / (s1 + 1e-8f);                                   \
    float w2 = 1.0f / (s2 + 1e-8f);                                   \
    float wsum = (w0 + w1) + w2;                                      \
    w0 = w0 / wsum; w1 = w1 / wsum; w2 = w2 / wsum;                   \
    float f0x = flow[i0*3+0], f0y = flow[i0*3+1], f0z = flow[i0*3+2]; \
    float f1x = flow[i1*3+0], f1y = flow[i1*3+1], f1z = flow[i1*3+2]; \
    float f2x = flow[i2*3+0], f2y = flow[i2*3+1], f2z = flow[i2*3+2]; \
    out[q*3+0] = (w0 * f0x + w1 * f1x) + w2 * f2x;                    \
    out[q*3+1] = (w0 * f0y + w1 * f1y) + w2 * f2y;                    \
    out[q*3+2] = (w0 * f0z + w1 * f1z) + w2 * f2z;                    \
} while (0)

__global__ __launch_bounds__(256) void zero_ints(int* __restrict__ p, int n) {
    int i = blockIdx.x * 256 + threadIdx.x;
    if (i < n) p[i] = 0;
}

__global__ __launch_bounds__(256) void bin_count(
    const float* __restrict__ ref, int* __restrict__ cnt, int Nr) {
    int j = blockIdx.x * 256 + threadIdx.x;
    if (j >= Nr) return;
    int cx = cell_coord(ref[3 * j + 0]);
    int cy = cell_coord(ref[3 * j + 1]);
    int cz = cell_coord(ref[3 * j + 2]);
    atomicAdd(&cnt[(cz * G + cy) * G + cx], 1);
}

// single-block exclusive scan over NCELLS = 1024 threads * 32 cells each
__global__ __launch_bounds__(1024) void scan_cells(
    const int* __restrict__ cnt, int* __restrict__ off, int* __restrict__ cur) {
    __shared__ int wsum[16];
    int tid = threadIdx.x, lane = tid & 63, wid = tid >> 6;
    int base = tid * 32;
    int local[32];
    int s = 0;
#pragma unroll
    for (int k = 0; k < 32; ++k) { local[k] = cnt[base + k]; s += local[k]; }
    int incl = s;
#pragma unroll
    for (int sh = 1; sh < 64; sh <<= 1) {
        int t = __shfl_up(incl, sh, 64);
        if (lane >= sh) incl += t;
    }
    if (lane == 63) wsum[wid] = incl;
    __syncthreads();
    if (wid == 0) {
        int w = (lane < 16) ? wsum[lane] : 0;
        int wincl = w;
#pragma unroll
        for (int sh = 1; sh < 16; sh <<= 1) {
            int t = __shfl_up(wincl, sh, 64);
            if (lane >= sh) wincl += t;
        }
        if (lane < 16) wsum[lane] = wincl - w;   // exclusive wave offset
    }
    __syncthreads();
    int run = wsum[wid] + incl - s;              // exclusive prefix
#pragma unroll
    for (int k = 0; k < 32; ++k) {
        off[base + k] = run;
        cur[base + k] = run;
        run += local[k];
    }
    if (tid == 1023) off[NCELLS] = run;
}

// scatter refs: sorted float4 (x,y,z, idx-as-bits)
__global__ __launch_bounds__(256) void bin_fill(
    const float* __restrict__ ref, int* __restrict__ cur,
    float4* __restrict__ srt, int Nr) {
    int j = blockIdx.x * 256 + threadIdx.x;
    if (j >= Nr) return;
    float x = ref[3 * j + 0], y = ref[3 * j + 1], z = ref[3 * j + 2];
    int cx = cell_coord(x), cy = cell_coord(y), cz = cell_coord(z);
    int cell = (cz * G + cy) * G + cx;
    int pos = atomicAdd(&cur[cell], 1);
    srt[pos] = make_float4(x, y, z, __int_as_float(j));
}

// ---------------------------------------------------------------------------
// 27-cell kNN, TWO queries per wave (32-lane groups). Per group: lanes 0..8
// fetch the 9 row bounds; width-32 prefix; 9 (prefix,base) pairs broadcast
// via width-32 shfl; one balanced loop over u in [0,total) with the proven
// u->srt bijection; MERGE32 (5 stages, both queries share the instructions).
// Accept iff e2_raw + DELTA < HH^2 (R10-proven exact, clamped refs included);
// else append to qlist for the ring fallback.
// ---------------------------------------------------------------------------
__global__ __launch_bounds__(256) void knn27(
    const float* __restrict__ qpts, const float4* __restrict__ srt,
    const int* __restrict__ off, const float* __restrict__ flow,
    float* __restrict__ out, int* __restrict__ qlist,
    int* __restrict__ nflag, int Nq) {
#pragma clang fp contract(off)
    int sl = threadIdx.x & 31;                     // sub-lane in 32-group
    int q  = blockIdx.x * 8 + (threadIdx.x >> 5);  // 8 queries per 256-block
    bool qv = q < Nq;
    int qc = qv ? q : 0;

    float qx = qpts[3 * qc + 0];                   // same addr across group
    float qy = qpts[3 * qc + 1];
    float qz = qpts[3 * qc + 2];
    float q2 = (qx * qx + qy * qy) + qz * qz;

    int cx = cell_coord(qx), cy = cell_coord(qy), cz = cell_coord(qz);

    // 9 row bounds fetched in parallel by sub-lanes 0..8
    int dz = sl / 3 - 1, dy = sl % 3 - 1;          // meaningful for sl<9
    int zr = cz + dz, yr = cy + dy;
    bool vrow = (sl < 9) && qv && (zr >= 0) && (zr < G) && (yr >= 0) && (yr < G);
    int xlo = imax2(cx - 1, 0), xhi = imin2(cx + 1, G - 1);
    int vlo = 0, vhi = 0;
    if (vrow) {
        int rowbase = (zr * G + yr) * G;
        vlo = off[rowbase + xlo];
        vhi = off[rowbase + xhi + 1];
    }
    int cnt = vhi - vlo;                           // 0 for sl >= 9 / invalid q

    // inclusive prefix within the 32-group (4 steps cover lanes 0..8)
    int incl = cnt;
#pragma unroll
    for (int sh = 1; sh <= 8; sh <<= 1) {
        int t = __shfl_up(incl, sh, 32);
        if (sl >= sh) incl += t;
    }
    int total = __shfl(incl, 8, 32);               // group-uniform
    int prex  = incl - cnt;                        // exclusive prefix

    // broadcast row boundaries & bases within the group
    int p1 = __shfl(prex, 1, 32), p2 = __shfl(prex, 2, 32);
    int p3 = __shfl(prex, 3, 32), p4 = __shfl(prex, 4, 32);
    int p5 = __shfl(prex, 5, 32), p6 = __shfl(prex, 6, 32);
    int p7 = __shfl(prex, 7, 32), p8 = __shfl(prex, 8, 32);
    int b0 = __shfl(vlo, 0, 32);                   // base - prefix per row
    int b1 = __shfl(vlo, 1, 32) - p1;
    int b2 = __shfl(vlo, 2, 32) - p2;
    int b3 = __shfl(vlo, 3, 32) - p3;
    int b4 = __shfl(vlo, 4, 32) - p4;
    int b5 = __shfl(vlo, 5, 32) - p5;
    int b6 = __shfl(vlo, 6, 32) - p6;
    int b7 = __shfl(vlo, 7, 32) - p7;
    int b8 = __shfl(vlo, 8, 32) - p8;

    const float FINF = __builtin_inff();
    float e0 = FINF, e1 = FINF, e2 = FINF;
    int   i0 = 0x7fffffff, i1 = 0x7fffffff, i2 = 0x7fffffff;

#pragma unroll 2
    for (int u = sl; u < total; u += 32) {
        int idx = u + b0;
        idx = (u >= p1) ? (u + b1) : idx;
        idx = (u >= p2) ? (u + b2) : idx;
        idx = (u >= p3) ? (u + b3) : idx;
        idx = (u >= p4) ? (u + b4) : idx;
        idx = (u >= p5) ? (u + b5) : idx;
        idx = (u >= p6) ? (u + b6) : idx;
        idx = (u >= p7) ? (u + b7) : idx;
        idx = (u >= p8) ? (u + b8) : idx;
        float4 rr = srt[idx];
        float xx = rr.x * rr.x;
        float yy = rr.y * rr.y;
        float zz = rr.z * rr.z;
        float r2 = (xx + yy) + zz;
        float td = qx * rr.x;
        td = fmaf(qy, rr.y, td);
        td = fmaf(qz, rr.z, td);
        float aa = q2 + r2;
        float dd = fmaf(-2.0f, td, aa);
        int jj = __float_as_int(rr.w);
        LEXINSERT(dd, jj);
    }

    MERGE32();                                     // raw (unclamped) merge

    bool ok = (e2 + DELTA < HH * HH);              // INF -> fail
    if (sl == 0 && qv) {
        if (ok) {
            EPILOGUE();
        } else {
            int pos = atomicAdd(nflag, 1);
            qlist[pos] = q;
        }
    }
}

// ---------------------------------------------------------------------------
// Ring fallback (R9-proven exact): grid-striding waves over the compact
// flagged-query list. Wave-uniform ring walk with conservative wave-min e2
// prune; face rows are contiguous srt runs. ~3-4% of queries land here.
// ---------------------------------------------------------------------------
__global__ __launch_bounds__(256) void knn_rings(
    const float* __restrict__ qpts, const float4* __restrict__ srt,
    const int* __restrict__ off, const int* __restrict__ qlist,
    const int* __restrict__ nflag, const float* __restrict__ flow,
    float* __restrict__ out) {
#pragma clang fp contract(off)
    int lane = threadIdx.x & 63;
    int wav  = (blockIdx.x * 256 + threadIdx.x) >> 6;
    int nWaves = (gridDim.x * 256) >> 6;
    int n = nflag[0];

    for (int f = wav; f < n; f += nWaves) {
        int q = qlist[f];
        float qx = rdfl(qpts[3 * q + 0]);
        float qy = rdfl(qpts[3 * q + 1]);
        float qz = rdfl(qpts[3 * q + 2]);
        float q2 = (qx * qx + qy * qy) + qz * qz;

        int cx = cell_coord(qx), cy = cell_coord(qy), cz = cell_coord(qz);
        float bx = LOF + cx * HH, by = LOF + cy * HH, bz = LOF + cz * HH;
        float fmin = qx - bx;                      // signed face distances
        fmin = fminf(fmin, (bx + HH) - qx);
        fmin = fminf(fmin, qy - by);
        fmin = fminf(fmin, (by + HH) - qy);
        fmin = fminf(fmin, qz - bz);
        fmin = fminf(fmin, (bz + HH) - qz);

        const float FINF = __builtin_inff();
        float e0 = FINF, e1 = FINF, e2 = FINF;
        int   i0 = 0x7fffffff, i1 = 0x7fffffff, i2 = 0x7fffffff;

        for (int m = 0; m < G; ++m) {
            if (m > 0) {
                float ge = e2;                     // wave-min e2 (conservative)
#pragma unroll
                for (int mk = 1; mk < 64; mk <<= 1)
                    ge = fminf(ge, __shfl_xor(ge, mk, 64));
                ge = rdfl(ge);
                float lb = fmaxf((float)(m - 1) * HH + fmin, 0.0f);
                if (lb * lb > ge + DELTA) break;   // wave-uniform break
            }
            if (m == 0) {
                int cell = (cz * G + cy) * G + cx;
                int lo = off[cell], hi = off[cell + 1];
                SCAN_RUN(lo, hi);
            } else {
                int zlo = imax2(cz - m, 0), zhi = imin2(cz + m, G - 1);
                int ylo = imax2(cy - m, 0), yhi = imin2(cy + m, G - 1);
                int xlo = imax2(cx - m, 0), xhi = imin2(cx + m, G - 1);
                for (int z = zlo; z <= zhi; ++z) {
                    int fz = (iabs(z - cz) == m);
                    for (int y = ylo; y <= yhi; ++y) {
                        int face = fz | (iabs(y - cy) == m);
                        int rowbase = (z * G + y) * G;
                        if (face) {                // contiguous run of cells
                            int lo = off[rowbase + xlo];
                            int hi = off[rowbase + xhi + 1];
                            SCAN_RUN(lo, hi);
                        } else {                   // only x = cx +- m
                            if (cx - m >= 0) {
                                int cell = rowbase + (cx - m);
                                int lo = off[cell], hi = off[cell + 1];
                                SCAN_RUN(lo, hi);
                            }
                            if (cx + m <= G - 1) {
                                int cell = rowbase + (cx + m);
                                int lo = off[cell], hi = off[cell + 1];
                                SCAN_RUN(lo, hi);
                            }
                        }
                    }
                }
            }
        }

        MERGE64();
        if (lane == 0) EPILOGUE();
    }
}

extern "C" void kernel_launch(void* const* d_in, const int* in_sizes, int n_in,
                              void* d_out, int out_size, void* d_ws, size_t ws_size,
                              hipStream_t stream) {
    const float* q    = (const float*)d_in[0];
    const float* ref  = (const float*)d_in[1];
    const float* flow = (const float*)d_in[2];
    float* out = (float*)d_out;

    int Nq = in_sizes[0] / 3;
    int Nr = in_sizes[1] / 3;

    char* ws = (char*)d_ws;
    float4* srt = (float4*)ws;                       // Nr float4 (16B aligned)
    size_t o = (size_t)Nr * sizeof(float4);
    int* off   = (int*)(ws + o);  o += (size_t)(NCELLS + 1) * sizeof(int);
    int* cur   = (int*)(ws + o);  o += (size_t)NCELLS * sizeof(int);
    int* cnt   = (int*)(ws + o);  o += (size_t)(NCELLS + 1) * sizeof(int);
    int* nflag = cnt + NCELLS;                       // zeroed with cnt
    int* qlist = (int*)(ws + o);  o += (size_t)Nq * sizeof(int);

    zero_ints<<<(NCELLS + 1 + 255) / 256, 256, 0, stream>>>(cnt, NCELLS + 1);
    bin_count<<<(Nr + 255) / 256, 256, 0, stream>>>(ref, cnt, Nr);
    scan_cells<<<1, 1024, 0, stream>>>(cnt, off, cur);
    bin_fill<<<(Nr + 255) / 256, 256, 0, stream>>>(ref, cur, srt, Nr);

    int nBlocks = (Nq + 7) / 8;                      // 8 queries (groups)/block
    knn27<<<nBlocks, 256, 0, stream>>>(q, srt, off, flow, out, qlist, nflag, Nq);
    knn_rings<<<256, 256, 0, stream>>>(q, srt, off, qlist, nflag, flow, out);
}

// Round 14
// 89.104 us; speedup vs baseline: 1.5372x; 1.5372x over previous
//
#include <hip/hip_runtime.h>
#include <math.h>

#define G      32
#define NCELLS (G * G * G)        // 32768
#define LOF    (-6.0f)
#define HH     0.375f             // 12/32
#define INVH   (1.0f / 0.375f)
#define DELTA  1e-3f              // accept slack >> fp d2 rounding (~1e-5)
#define NCHUNK 16                 // fallback ref-chunks per query

__device__ __forceinline__ int cell_coord(float x) {
    int c = (int)floorf((x - LOF) * INVH);
    c = c < 0 ? 0 : c;
    return c > G - 1 ? G - 1 : c;
}
__device__ __forceinline__ int imax2(int a, int b) { return a > b ? a : b; }
__device__ __forceinline__ int imin2(int a, int b) { return a < b ? a : b; }
__device__ __forceinline__ float rdfl(float v) {
    return __int_as_float(__builtin_amdgcn_readfirstlane(__float_as_int(v)));
}

// lexicographic (d, idx) 3-slot insert == jax top_k tie semantics (order-free)
#define LEXINSERT(dv, jv) do {                                        \
    float d_ = (dv); int j_ = (jv);                                   \
    bool l0 = (d_ < e0) || ((d_ == e0) && (j_ < i0));                 \
    bool l1 = (d_ < e1) || ((d_ == e1) && (j_ < i1));                 \
    bool l2 = (d_ < e2) || ((d_ == e2) && (j_ < i2));                 \
    int   ni0 = l0 ? j_ : i0;                                         \
    int   ni1 = l0 ? i0 : (l1 ? j_ : i1);                             \
    int   ni2 = l1 ? i1 : (l2 ? j_ : i2);                             \
    float ne0 = l0 ? d_ : e0;                                         \
    float ne1 = l0 ? e0 : (l1 ? d_ : e1);                             \
    float ne2 = l1 ? e1 : (l2 ? d_ : e2);                             \
    e0 = ne0; e1 = ne1; e2 = ne2; i0 = ni0; i1 = ni1; i2 = ni2;       \
} while (0)

// lanes split refs [lo,hi) of a contiguous run; coalesced float4 loads.
// d2 chain bit-identical to the passing kernels (contract off in caller).
#define SCAN_RUN(lo_, hi_) do {                                       \
    for (int u = (lo_) + lane; u < (hi_); u += 64) {                  \
        float4 rr = srt[u];                                           \
        float xx = rr.x * rr.x;                                       \
        float yy = rr.y * rr.y;                                       \
        float zz = rr.z * rr.z;                                       \
        float r2 = (xx + yy) + zz;                                    \
        float td = qx * rr.x;                                         \
        td = fmaf(qy, rr.y, td);                                      \
        td = fmaf(qz, rr.z, td);                                      \
        float aa = q2 + r2;                                           \
        float dd = fmaf(-2.0f, td, aa);                               \
        int jj = __float_as_int(rr.w);                                \
        LEXINSERT(dd, jj);                                            \
    }                                                                 \
} while (0)

// 64-lane butterfly lex-merge of per-lane top-3 sets
#define MERGE64() do {                                                \
    _Pragma("unroll")                                                 \
    for (int mk_ = 1; mk_ < 64; mk_ <<= 1) {                          \
        float f0 = __shfl_xor(e0, mk_, 64);                           \
        float f1 = __shfl_xor(e1, mk_, 64);                           \
        float f2 = __shfl_xor(e2, mk_, 64);                           \
        int   g0 = __shfl_xor(i0, mk_, 64);                           \
        int   g1 = __shfl_xor(i1, mk_, 64);                           \
        int   g2 = __shfl_xor(i2, mk_, 64);                           \
        LEXINSERT(f0, g0);                                            \
        LEXINSERT(f1, g1);                                            \
        LEXINSERT(f2, g2);                                            \
    }                                                                 \
} while (0)

// 32-lane butterfly: masks 1..16 never cross the 32-lane group boundary, so
// the SAME instructions merge both queries of the wave simultaneously.
#define MERGE32() do {                                                \
    _Pragma("unroll")                                                 \
    for (int mk_ = 1; mk_ < 32; mk_ <<= 1) {                          \
        float f0 = __shfl_xor(e0, mk_, 64);                           \
        float f1 = __shfl_xor(e1, mk_, 64);                           \
        float f2 = __shfl_xor(e2, mk_, 64);                           \
        int   g0 = __shfl_xor(i0, mk_, 64);                           \
        int   g1 = __shfl_xor(i1, mk_, 64);                           \
        int   g2 = __shfl_xor(i2, mk_, 64);                           \
        LEXINSERT(f0, g0);                                            \
        LEXINSERT(f1, g1);                                            \
        LEXINSERT(f2, g2);                                            \
    }                                                                 \
} while (0)

// clamp + weights + gather + store, reference op order
#define EPILOGUE() do {                                               \
    e0 = fmaxf(e0, 0.0f);                                             \
    e1 = fmaxf(e1, 0.0f);                                             \
    e2 = fmaxf(e2, 0.0f);                                             \
    float s0 = sqrtf(e0);                                             \
    float s1 = sqrtf(e1);                                             \
    float s2 = sqrtf(e2);                                             \
    float w0 = 1.0f / (s0 + 1e-8f);                                   \
    float w1 = 1.0f / (s1 + 1e-8f);                                   \
    float w2 = 1.0f / (s2 + 1e-8f);                                   \
    float wsum = (w0 + w1) + w2;                                      \
    w0 = w0 / wsum; w1 = w1 / wsum; w2 = w2 / wsum;                   \
    float f0x = flow[i0*3+0], f0y = flow[i0*3+1], f0z = flow[i0*3+2]; \
    float f1x = flow[i1*3+0], f1y = flow[i1*3+1], f1z = flow[i1*3+2]; \
    float f2x = flow[i2*3+0], f2y = flow[i2*3+1], f2z = flow[i2*3+2]; \
    out[q*3+0] = (w0 * f0x + w1 * f1x) + w2 * f2x;                    \
    out[q*3+1] = (w0 * f0y + w1 * f1y) + w2 * f2y;                    \
    out[q*3+2] = (w0 * f0z + w1 * f1z) + w2 * f2z;                    \
} while (0)

__global__ __launch_bounds__(256) void zero_ints(int* __restrict__ p, int n) {
    int i = blockIdx.x * 256 + threadIdx.x;
    if (i < n) p[i] = 0;
}

__global__ __launch_bounds__(256) void bin_count(
    const float* __restrict__ ref, int* __restrict__ cnt, int Nr) {
    int j = blockIdx.x * 256 + threadIdx.x;
    if (j >= Nr) return;
    int cx = cell_coord(ref[3 * j + 0]);
    int cy = cell_coord(ref[3 * j + 1]);
    int cz = cell_coord(ref[3 * j + 2]);
    atomicAdd(&cnt[(cz * G + cy) * G + cx], 1);
}

// single-block exclusive scan over NCELLS = 1024 threads * 32 cells each
__global__ __launch_bounds__(1024) void scan_cells(
    const int* __restrict__ cnt, int* __restrict__ off, int* __restrict__ cur) {
    __shared__ int wsum[16];
    int tid = threadIdx.x, lane = tid & 63, wid = tid >> 6;
    int base = tid * 32;
    int local[32];
    int s = 0;
#pragma unroll
    for (int k = 0; k < 32; ++k) { local[k] = cnt[base + k]; s += local[k]; }
    int incl = s;
#pragma unroll
    for (int sh = 1; sh < 64; sh <<= 1) {
        int t = __shfl_up(incl, sh, 64);
        if (lane >= sh) incl += t;
    }
    if (lane == 63) wsum[wid] = incl;
    __syncthreads();
    if (wid == 0) {
        int w = (lane < 16) ? wsum[lane] : 0;
        int wincl = w;
#pragma unroll
        for (int sh = 1; sh < 16; sh <<= 1) {
            int t = __shfl_up(wincl, sh, 64);
            if (lane >= sh) wincl += t;
        }
        if (lane < 16) wsum[lane] = wincl - w;   // exclusive wave offset
    }
    __syncthreads();
    int run = wsum[wid] + incl - s;              // exclusive prefix
#pragma unroll
    for (int k = 0; k < 32; ++k) {
        off[base + k] = run;
        cur[base + k] = run;
        run += local[k];
    }
    if (tid == 1023) off[NCELLS] = run;
}

// scatter refs: sorted float4 (x,y,z, idx-as-bits)
__global__ __launch_bounds__(256) void bin_fill(
    const float* __restrict__ ref, int* __restrict__ cur,
    float4* __restrict__ srt, int Nr) {
    int j = blockIdx.x * 256 + threadIdx.x;
    if (j >= Nr) return;
    float x = ref[3 * j + 0], y = ref[3 * j + 1], z = ref[3 * j + 2];
    int cx = cell_coord(x), cy = cell_coord(y), cz = cell_coord(z);
    int cell = (cz * G + cy) * G + cx;
    int pos = atomicAdd(&cur[cell], 1);
    srt[pos] = make_float4(x, y, z, __int_as_float(j));
}

// ---------------------------------------------------------------------------
// 27-cell kNN, TWO queries per wave (32-lane groups, R13-passing). Lanes 0..8
// fetch row bounds; width-32 prefix; one balanced loop with the proven
// u->srt bijection; MERGE32 (both queries share the merge instructions).
// Accept iff e2_raw + DELTA < HH^2 (R10-proven exact); else append to qlist.
// ---------------------------------------------------------------------------
__global__ __launch_bounds__(256) void knn27(
    const float* __restrict__ qpts, const float4* __restrict__ srt,
    const int* __restrict__ off, const float* __restrict__ flow,
    float* __restrict__ out, int* __restrict__ qlist,
    int* __restrict__ nflag, int Nq) {
#pragma clang fp contract(off)
    int sl = threadIdx.x & 31;                     // sub-lane in 32-group
    int q  = blockIdx.x * 8 + (threadIdx.x >> 5);  // 8 queries per 256-block
    bool qv = q < Nq;
    int qc = qv ? q : 0;

    float qx = qpts[3 * qc + 0];                   // same addr across group
    float qy = qpts[3 * qc + 1];
    float qz = qpts[3 * qc + 2];
    float q2 = (qx * qx + qy * qy) + qz * qz;

    int cx = cell_coord(qx), cy = cell_coord(qy), cz = cell_coord(qz);

    // 9 row bounds fetched in parallel by sub-lanes 0..8
    int dz = sl / 3 - 1, dy = sl % 3 - 1;          // meaningful for sl<9
    int zr = cz + dz, yr = cy + dy;
    bool vrow = (sl < 9) && qv && (zr >= 0) && (zr < G) && (yr >= 0) && (yr < G);
    int xlo = imax2(cx - 1, 0), xhi = imin2(cx + 1, G - 1);
    int vlo = 0, vhi = 0;
    if (vrow) {
        int rowbase = (zr * G + yr) * G;
        vlo = off[rowbase + xlo];
        vhi = off[rowbase + xhi + 1];
    }
    int cnt = vhi - vlo;                           // 0 for sl >= 9 / invalid q

    // inclusive prefix within the 32-group (4 steps cover lanes 0..8)
    int incl = cnt;
#pragma unroll
    for (int sh = 1; sh <= 8; sh <<= 1) {
        int t = __shfl_up(incl, sh, 32);
        if (sl >= sh) incl += t;
    }
    int total = __shfl(incl, 8, 32);               // group-uniform
    int prex  = incl - cnt;                        // exclusive prefix

    // broadcast row boundaries & bases within the group
    int p1 = __shfl(prex, 1, 32), p2 = __shfl(prex, 2, 32);
    int p3 = __shfl(prex, 3, 32), p4 = __shfl(prex, 4, 32);
    int p5 = __shfl(prex, 5, 32), p6 = __shfl(prex, 6, 32);
    int p7 = __shfl(prex, 7, 32), p8 = __shfl(prex, 8, 32);
    int b0 = __shfl(vlo, 0, 32);                   // base - prefix per row
    int b1 = __shfl(vlo, 1, 32) - p1;
    int b2 = __shfl(vlo, 2, 32) - p2;
    int b3 = __shfl(vlo, 3, 32) - p3;
    int b4 = __shfl(vlo, 4, 32) - p4;
    int b5 = __shfl(vlo, 5, 32) - p5;
    int b6 = __shfl(vlo, 6, 32) - p6;
    int b7 = __shfl(vlo, 7, 32) - p7;
    int b8 = __shfl(vlo, 8, 32) - p8;

    const float FINF = __builtin_inff();
    float e0 = FINF, e1 = FINF, e2 = FINF;
    int   i0 = 0x7fffffff, i1 = 0x7fffffff, i2 = 0x7fffffff;

#pragma unroll 2
    for (int u = sl; u < total; u += 32) {
        int idx = u + b0;
        idx = (u >= p1) ? (u + b1) : idx;
        idx = (u >= p2) ? (u + b2) : idx;
        idx = (u >= p3) ? (u + b3) : idx;
        idx = (u >= p4) ? (u + b4) : idx;
        idx = (u >= p5) ? (u + b5) : idx;
        idx = (u >= p6) ? (u + b6) : idx;
        idx = (u >= p7) ? (u + b7) : idx;
        idx = (u >= p8) ? (u + b8) : idx;
        float4 rr = srt[idx];
        float xx = rr.x * rr.x;
        float yy = rr.y * rr.y;
        float zz = rr.z * rr.z;
        float r2 = (xx + yy) + zz;
        float td = qx * rr.x;
        td = fmaf(qy, rr.y, td);
        td = fmaf(qz, rr.z, td);
        float aa = q2 + r2;
        float dd = fmaf(-2.0f, td, aa);
        int jj = __float_as_int(rr.w);
        LEXINSERT(dd, jj);
    }

    MERGE32();                                     // raw (unclamped) merge

    bool ok = (e2 + DELTA < HH * HH);              // INF -> fail
    if (sl == 0 && qv) {
        if (ok) {
            EPILOGUE();
        } else {
            int pos = atomicAdd(nflag, 1);
            qlist[pos] = q;
        }
    }
}

// ---------------------------------------------------------------------------
// Fallback stage 1 (R11/R12-proven): grid-striding waves over (flagged query,
// ref-chunk) items — bounded parallel work, no serial straggler. Each wave
// scans one 1/NCHUNK slice of all refs and writes its top-3 to cand.
// ---------------------------------------------------------------------------
__global__ __launch_bounds__(256) void brute_chunk(
    const float* __restrict__ qpts, const float4* __restrict__ srt,
    const int* __restrict__ qlist, const int* __restrict__ nflag,
    float2* __restrict__ cand, int Nr) {
#pragma clang fp contract(off)
    int lane = threadIdx.x & 63;
    int wav  = (blockIdx.x * 256 + threadIdx.x) >> 6;
    int nWaves = (gridDim.x * 256) >> 6;
    int nItems = nflag[0] * NCHUNK;
    int CS = (Nr + NCHUNK - 1) / NCHUNK;

    for (int item = wav; item < nItems; item += nWaves) {
        int f = item / NCHUNK;
        int chunk = item - f * NCHUNK;
        int q = qlist[f];
        float qx = rdfl(qpts[3 * q + 0]);
        float qy = rdfl(qpts[3 * q + 1]);
        float qz = rdfl(qpts[3 * q + 2]);
        float q2 = (qx * qx + qy * qy) + qz * qz;

        int lo = chunk * CS;
        int hi = imin2(lo + CS, Nr);

        const float FINF = __builtin_inff();
        float e0 = FINF, e1 = FINF, e2 = FINF;
        int   i0 = 0x7fffffff, i1 = 0x7fffffff, i2 = 0x7fffffff;

        SCAN_RUN(lo, hi);
        MERGE64();

        if (lane == 0) {
            cand[item * 3 + 0] = make_float2(e0, __int_as_float(i0));
            cand[item * 3 + 1] = make_float2(e1, __int_as_float(i1));
            cand[item * 3 + 2] = make_float2(e2, __int_as_float(i2));
        }
    }
}

// ---------------------------------------------------------------------------
// Fallback stage 2: one wave per flagged query (grid-striding). Lanes 0..47
// load the 48 chunk-candidates in parallel; butterfly lex-merge; epilogue.
// Union of per-chunk top-3 contains the global top-3; LEXINSERT order-free.
// ---------------------------------------------------------------------------
__global__ __launch_bounds__(256) void brute_merge(
    const int* __restrict__ qlist, const int* __restrict__ nflag,
    const float2* __restrict__ cand, const float* __restrict__ flow,
    float* __restrict__ out) {
#pragma clang fp contract(off)
    int lane = threadIdx.x & 63;
    int wav  = (blockIdx.x * 256 + threadIdx.x) >> 6;
    int nWaves = (gridDim.x * 256) >> 6;
    int n = nflag[0];

    for (int f = wav; f < n; f += nWaves) {
        int q = qlist[f];
        const float FINF = __builtin_inff();
        float e0 = FINF, e1 = FINF, e2 = FINF;
        int   i0 = 0x7fffffff, i1 = 0x7fffffff, i2 = 0x7fffffff;
        if (lane < 3 * NCHUNK) {
            float2 cc = cand[f * (3 * NCHUNK) + lane];
            e0 = cc.x;
            i0 = __float_as_int(cc.y);
        }
        MERGE64();
        if (lane == 0) EPILOGUE();
    }
}

extern "C" void kernel_launch(void* const* d_in, const int* in_sizes, int n_in,
                              void* d_out, int out_size, void* d_ws, size_t ws_size,
                              hipStream_t stream) {
    const float* q    = (const float*)d_in[0];
    const float* ref  = (const float*)d_in[1];
    const float* flow = (const float*)d_in[2];
    float* out = (float*)d_out;

    int Nq = in_sizes[0] / 3;
    int Nr = in_sizes[1] / 3;

    char* ws = (char*)d_ws;
    float4* srt = (float4*)ws;                       // Nr float4 (16B aligned)
    size_t o = (size_t)Nr * sizeof(float4);
    int* off   = (int*)(ws + o);  o += (size_t)(NCELLS + 1) * sizeof(int);
    int* cur   = (int*)(ws + o);  o += (size_t)NCELLS * sizeof(int);
    int* cnt   = (int*)(ws + o);  o += (size_t)(NCELLS + 1) * sizeof(int);
    int* nflag = cnt + NCELLS;                       // zeroed with cnt
    int* qlist = (int*)(ws + o);  o += (size_t)Nq * sizeof(int);
    o = (o + 15) & ~(size_t)15;
    float2* cand = (float2*)(ws + o);                // Nq*48 float2 worst case
    o += (size_t)Nq * 3 * NCHUNK * sizeof(float2);

    zero_ints<<<(NCELLS + 1 + 255) / 256, 256, 0, stream>>>(cnt, NCELLS + 1);
    bin_count<<<(Nr + 255) / 256, 256, 0, stream>>>(ref, cnt, Nr);
    scan_cells<<<1, 1024, 0, stream>>>(cnt, off, cur);
    bin_fill<<<(Nr + 255) / 256, 256, 0, stream>>>(ref, cur, srt, Nr);

    int nBlocks = (Nq + 7) / 8;                      // 8 queries (groups)/block
    knn27<<<nBlocks, 256, 0, stream>>>(q, srt, off, flow, out, qlist, nflag, Nq);
    brute_chunk<<<1024, 256, 0, stream>>>(q, srt, qlist, nflag, cand, Nr);
    brute_merge<<<256, 256, 0, stream>>>(qlist, nflag, cand, flow, out);
}